// Round 11
// baseline (74.529 us; speedup 1.0000x reference)
//
#include <hip/hip_runtime.h>

typedef __attribute__((ext_vector_type(8))) short bf16x8;
typedef __attribute__((ext_vector_type(4))) float f32x4;

__device__ __forceinline__ unsigned short f2bf(float f) {
  unsigned int u = __float_as_uint(f);
  return (unsigned short)((u + 0x7fffu + ((u >> 16) & 1u)) >> 16);  // RNE
}

__device__ __forceinline__ float bf2f(unsigned short s) {
  return __uint_as_float(((unsigned int)s) << 16);
}

__device__ __forceinline__ unsigned int cvtpk(float a, float b) {
  unsigned int w;  // [bf16(a) lo16, bf16(b) hi16], HW RNE
  asm("v_cvt_pk_bf16_f32 %0, %1, %2" : "=v"(w) : "v"(a), "v"(b));
  return w;
}

__device__ __forceinline__ void gload_lds16(const void* g, void* l) {
  __builtin_amdgcn_global_load_lds((const __attribute__((address_space(1))) void*)g,
                                   (__attribute__((address_space(3))) void*)l,
                                   16, 0, 0);
}

// prep (R8-proven): (a) gather U into fragment-ordered Upk; (b) cast V -> bf16.
// Upk[((jg*16 + n)*64 + l)*8 + e] = U[n*16 + (l&15)][jg*32 + (l>>4)*8 + e]
__global__ void prep(const float* __restrict__ U, const float4* __restrict__ V,
                     unsigned short* __restrict__ Upk, ushort4* __restrict__ Vb) {
  int i = blockIdx.x * 256 + threadIdx.x;
  const int NUP = 128 * 16 * 64;  // 131072 fragment-octets
  if (i < NUP) {
    int l = i & 63, n = (i >> 6) & 15, jg = i >> 10;
    const float* src = U + (long long)(n * 16 + (l & 15)) * 4096 + jg * 32 + (l >> 4) * 8;
    float4 a = *(const float4*)src;
    float4 b = *(const float4*)(src + 4);
    ushort4 o0, o1;
    o0.x = f2bf(a.x); o0.y = f2bf(a.y); o0.z = f2bf(a.z); o0.w = f2bf(a.w);
    o1.x = f2bf(b.x); o1.y = f2bf(b.y); o1.z = f2bf(b.z); o1.w = f2bf(b.w);
    ushort4* d = (ushort4*)(Upk + (long long)i * 8);
    d[0] = o0; d[1] = o1;
  } else {
    int j = i - NUP;  // 262144 float4s of V
    float4 v = V[j];
    ushort4 o;
    o.x = f2bf(v.x); o.y = f2bf(v.y); o.z = f2bf(v.z); o.w = f2bf(v.w);
    Vb[j] = o;
  }
}

// ---------------------------------------------------------------------------
// GEMM1 "direct": P[z][m][r] = sum_k x[m, z*256+k] * U[r, z*256+k]
// NO LDS, NO barriers. x: global->VGPR 2 steps ahead, cvt_pk at use.
// U: B-fragments read DIRECTLY from global Upk (2MB, L2-resident; each frag
// read is 16B/lane = 1KB/wave contiguous).
// FIX vs round 10: consume xr[j&1] into SSA locals BEFORE issuing
// XPRE(j+2, (j+2)&1) — same parity means the prefetch overwrites step j's
// buffer; the old order fed step j with step j+2's data (absmax 7.2).
// ---------------------------------------------------------------------------
__global__ __launch_bounds__(256, 2)
void gemm1_direct(const float* __restrict__ x, const unsigned short* __restrict__ Upk,
                  unsigned short* __restrict__ P) {
  const int tid = threadIdx.x;
  const int l = tid & 63;
  const int w = tid >> 6;
  const int mg = blockIdx.x;  // 32 m-groups of 128 rows
  const int z = blockIdx.z;   // 16 K-chunks of 256
  const int lr = l & 15;
  const int lg = l >> 4;

  const float* xb = x + (long long)(mg * 128 + w * 32 + lr) * 4096 + z * 256 + lg * 8;
  const unsigned short* uz = Upk + ((long long)(z * 8) * 16 * 64 + l) * 8;

  float4 xr[2][4];  // [step parity][2 m-tiles x 2 float4] — static-indexed

#define XPRE(J, S)                                            \
  {                                                           \
    const float* p0_ = xb + (J) * 32;                         \
    const float* p1_ = p0_ + 16 * 4096;                       \
    xr[S][0] = *(const float4*)p0_;                           \
    xr[S][1] = *(const float4*)(p0_ + 4);                     \
    xr[S][2] = *(const float4*)p1_;                           \
    xr[S][3] = *(const float4*)(p1_ + 4);                     \
  }

  f32x4 acc0[16] = {};
  f32x4 acc1[16] = {};

  XPRE(0, 0);
  XPRE(1, 1);

#pragma unroll
  for (int j = 0; j < 8; ++j) {
    // CONSUME FIRST (SSA copies), then prefetch into the same-parity slot.
    float4 a0 = xr[j & 1][0], a1 = xr[j & 1][1];
    float4 a2 = xr[j & 1][2], a3 = xr[j & 1][3];
    if (j + 2 < 8) XPRE(j + 2, (j + 2) & 1);
    unsigned int w0 = cvtpk(a0.x, a0.y), w1 = cvtpk(a0.z, a0.w);
    unsigned int w2 = cvtpk(a1.x, a1.y), w3 = cvtpk(a1.z, a1.w);
    uint4 pk0 = {w0, w1, w2, w3};
    bf16x8 af0 = __builtin_bit_cast(bf16x8, pk0);
    unsigned int w4 = cvtpk(a2.x, a2.y), w5 = cvtpk(a2.z, a2.w);
    unsigned int w6 = cvtpk(a3.x, a3.y), w7 = cvtpk(a3.z, a3.w);
    uint4 pk1 = {w4, w5, w6, w7};
    bf16x8 af1 = __builtin_bit_cast(bf16x8, pk1);
    const unsigned short* uj = uz + j * 16 * 512;
#pragma unroll
    for (int n = 0; n < 16; ++n) {
      bf16x8 b = *(const bf16x8*)(uj + n * 512);
      acc0[n] = __builtin_amdgcn_mfma_f32_16x16x32_bf16(af0, b, acc0[n], 0, 0, 0);
      acc1[n] = __builtin_amdgcn_mfma_f32_16x16x32_bf16(af1, b, acc1[n], 0, 0, 0);
    }
  }
#undef XPRE

  // Epilogue: bf16 partials. C/D: col(N) = lane&15, row(M) = (lane>>4)*4 + reg.
  unsigned short* Pz = P + (long long)z * (4096LL * 256);
  const int r0 = mg * 128 + w * 32 + lg * 4;
#pragma unroll
  for (int n = 0; n < 16; ++n) {
    const int cc = n * 16 + lr;
#pragma unroll
    for (int i = 0; i < 4; ++i) {
      Pz[(long long)(r0 + i) * 256 + cc] = f2bf(acc0[n][i]);
      Pz[(long long)(r0 + 16 + i) * 256 + cc] = f2bf(acc1[n][i]);
    }
  }
}

// Sum 16 bf16 split-K partial slices -> bf16 t (fp32 accumulate)
__global__ void reduce16(const ushort4* __restrict__ P, ushort4* __restrict__ t) {
  const int S = 4096 * 256 / 4;
  int i = blockIdx.x * 256 + threadIdx.x;
  float sx = 0, sy = 0, sz = 0, sw = 0;
#pragma unroll
  for (int z = 0; z < 16; ++z) {
    ushort4 v = P[i + z * S];
    sx += bf2f(v.x); sy += bf2f(v.y); sz += bf2f(v.z); sw += bf2f(v.w);
  }
  ushort4 o;
  o.x = f2bf(sx); o.y = f2bf(sy); o.z = f2bf(sz); o.w = f2bf(sw);
  t[i] = o;
}

// ---------------------------------------------------------------------------
// GEMM2 (R9, proven): out = t @ V^T + bias, fp32 out. BM=BN=128, nkt=8.
// XOR-swizzled LDS tiles (both-sides).
// ---------------------------------------------------------------------------
__global__ __launch_bounds__(256)
void gemm2(const unsigned short* __restrict__ A,
           const unsigned short* __restrict__ B,
           const float* __restrict__ bias,
           float* __restrict__ C) {
  __shared__ __align__(16) unsigned short sA[2][128 * 32];
  __shared__ __align__(16) unsigned short sB[2][128 * 32];

  const int tid = threadIdx.x;
  const int l = tid & 63;
  const int w = tid >> 6;
  const int wm = (w >> 1) * 64;
  const int wn = (w & 1) * 64;
  const int rm = blockIdx.x * 128;
  const int rn = blockIdx.y * 128;
  const int lr = l & 15;
  const int lg = l >> 4;

  auto stage = [&](int kt, int buf) {
    const int k0 = kt * 32;
#pragma unroll
    for (int is = 0; is < 2; ++is) {
      int s = is * 256 + tid;
      int r = s >> 2;
      gload_lds16(B + (long long)(rn + r) * 256 + k0 + 8 * ((s & 3) ^ (r & 3)),
                  (char*)sB[buf] + s * 16);
    }
#pragma unroll
    for (int is = 0; is < 2; ++is) {
      int s = is * 256 + tid;
      int r = s >> 2;
      gload_lds16(A + (long long)(rm + r) * 256 + k0 + 8 * ((s & 3) ^ (r & 3)),
                  (char*)sA[buf] + s * 16);
    }
  };

  f32x4 acc[4][4] = {};

  stage(0, 0);
  for (int kt = 0; kt < 8; ++kt) {
    __syncthreads();
    if (kt < 7) stage(kt + 1, (kt + 1) & 1);
    const char* a0 = (const char*)sA[kt & 1];
    const char* b0 = (const char*)sB[kt & 1];
    bf16x8 af[4], bfr[4];
#pragma unroll
    for (int m = 0; m < 4; ++m) {
      const int row = wm + m * 16 + lr;
      af[m] = *(const bf16x8*)(a0 + row * 64 + ((lg * 16) ^ ((row & 3) << 4)));
    }
#pragma unroll
    for (int n = 0; n < 4; ++n) {
      const int row = wn + n * 16 + lr;
      bfr[n] = *(const bf16x8*)(b0 + row * 64 + ((lg * 16) ^ ((row & 3) << 4)));
    }
#pragma unroll
    for (int m = 0; m < 4; ++m)
#pragma unroll
      for (int n = 0; n < 4; ++n)
        acc[m][n] = __builtin_amdgcn_mfma_f32_16x16x32_bf16(af[m], bfr[n], acc[m][n], 0, 0, 0);
  }

  const int r0 = rm + wm + lg * 4;
  const int c0 = rn + wn + lr;
#pragma unroll
  for (int n = 0; n < 4; ++n) {
    const int cc = c0 + n * 16;
    const float badd = bias[cc];
#pragma unroll
    for (int m = 0; m < 4; ++m)
#pragma unroll
      for (int i = 0; i < 4; ++i)
        C[(long long)(r0 + m * 16 + i) * 4096 + cc] = acc[m][n][i] + badd;
  }
}

extern "C" void kernel_launch(void* const* d_in, const int* in_sizes, int n_in,
                              void* d_out, int out_size, void* d_ws, size_t ws_size,
                              hipStream_t stream) {
  const float* x    = (const float*)d_in[0];  // [4096,4096]
  const float* U    = (const float*)d_in[1];  // [256,4096]
  const float* V    = (const float*)d_in[2];  // [4096,256]
  const float* bias = (const float*)d_in[3];  // [4096]
  float* out = (float*)d_out;                 // [4096,4096] fp32

  // Workspace (38 MB):
  //  [0,32MB)   P: bf16 split-K partials [16][4096][256]
  //  [32,34MB)  t bf16 [4096][256]
  //  [34,36MB)  Upk bf16 fragment-ordered [128][16][64][8]
  //  [36,38MB)  V bf16 [4096][256]
  char* ws = (char*)d_ws;
  unsigned short* P   = (unsigned short*)ws;
  unsigned short* tb  = (unsigned short*)(ws + (32u << 20));
  unsigned short* Upk = (unsigned short*)(ws + (34u << 20));
  unsigned short* Vb  = (unsigned short*)(ws + (36u << 20));

  prep<<<1536, 256, 0, stream>>>(U, (const float4*)V, Upk, (ushort4*)Vb);

  // GEMM1: grid 32 m-groups x 16 z = 512 blocks (2/CU).
  dim3 g1(32, 1, 16);
  gemm1_direct<<<g1, 256, 0, stream>>>(x, Upk, P);

  reduce16<<<1024, 256, 0, stream>>>((const ushort4*)P, (ushort4*)tb);

  // GEMM2: grid 32x32.
  dim3 g2(32, 32, 1);
  gemm2<<<g2, 256, 0, stream>>>(tb, Vb, bias, out);
}

// Round 12
// 65.148 us; speedup vs baseline: 1.1440x; 1.1440x over previous
//
#include <hip/hip_runtime.h>

typedef __attribute__((ext_vector_type(8))) short bf16x8;
typedef __attribute__((ext_vector_type(4))) float f32x4;

__device__ __forceinline__ unsigned short f2bf(float f) {
  unsigned int u = __float_as_uint(f);
  return (unsigned short)((u + 0x7fffu + ((u >> 16) & 1u)) >> 16);  // RNE
}

__device__ __forceinline__ float bf2f(unsigned short s) {
  return __uint_as_float(((unsigned int)s) << 16);
}

__device__ __forceinline__ void gload_lds16(const void* g, void* l) {
  __builtin_amdgcn_global_load_lds((const __attribute__((address_space(1))) void*)g,
                                   (__attribute__((address_space(3))) void*)l,
                                   16, 0, 0);
}

// prep: cast x, U, V fp32 -> bf16 in one grid-stride pass (float4/ushort4).
__global__ void prep(const float4* __restrict__ x, const float4* __restrict__ U,
                     const float4* __restrict__ V, ushort4* __restrict__ xb,
                     ushort4* __restrict__ Ub, ushort4* __restrict__ Vb) {
  const int NX = 4096 * 4096 / 4;  // 4194304
  const int NU = 256 * 4096 / 4;   // 262144 each for U and V
  int i = blockIdx.x * 256 + threadIdx.x;
  const int stride = gridDim.x * 256;
  for (; i < NX + 2 * NU; i += stride) {
    const float4* s; ushort4* d; int j;
    if (i < NX)           { s = x; d = xb; j = i; }
    else if (i < NX + NU) { s = U; d = Ub; j = i - NX; }
    else                  { s = V; d = Vb; j = i - NX - NU; }
    float4 v = s[j];
    ushort4 o;
    o.x = f2bf(v.x); o.y = f2bf(v.y); o.z = f2bf(v.z); o.w = f2bf(v.w);
    d[j] = o;
  }
}

// ---------------------------------------------------------------------------
// GEMM1 (clone of the proven gemm2 skeleton, all-bf16):
//   P[z][m][r] = sum_{k<512} xb[m, z*512+k] * Ub[r, z*512+k]   (bf16 partials)
// BM=64, BN=256, BK=32, nkt=16, z=8. Waves 1x4 (wave tile 64x64, MREP=NREP=4,
// 16 MFMA vs 8 ds_read_b128 per step). LDS 40KB -> 4 blocks/CU capacity;
// grid 64x1x8 = 512 blocks (2/CU). XOR-swizzle both-sides on both tiles.
// ---------------------------------------------------------------------------
__global__ __launch_bounds__(256)
void gemm1_bf16(const unsigned short* __restrict__ A,   // xb [4096][4096]
                const unsigned short* __restrict__ B,   // Ub [256][4096]
                unsigned short* __restrict__ P) {
  __shared__ __align__(16) unsigned short sA[2][64 * 32];    // 2 x 4 KB
  __shared__ __align__(16) unsigned short sB[2][256 * 32];   // 2 x 16 KB

  const int tid = threadIdx.x;
  const int l = tid & 63;
  const int w = tid >> 6;
  const int wn = w * 64;           // 1x4 waves: wm = 0
  const int rm = blockIdx.x * 64;
  const int k0base = blockIdx.z * 512;
  const int lr = l & 15;
  const int lg = l >> 4;

  auto stage = [&](int kt, int buf) {
    const int k0 = k0base + kt * 32;
    // B: 1024 slots of 16B. slot s: row r=s>>2, swizzled col 8*((s&3)^(r&3)).
#pragma unroll
    for (int is = 0; is < 4; ++is) {
      int s = is * 256 + tid;
      int r = s >> 2;
      gload_lds16(B + (long long)r * 4096 + k0 + 8 * ((s & 3) ^ (r & 3)),
                  (char*)sB[buf] + s * 16);
    }
    // A: 256 slots. same swizzle.
    {
      int s = tid;
      int r = s >> 2;
      gload_lds16(A + (long long)(rm + r) * 4096 + k0 + 8 * ((s & 3) ^ (r & 3)),
                  (char*)sA[buf] + s * 16);
    }
  };

  f32x4 acc[4][4] = {};

  stage(0, 0);
  for (int kt = 0; kt < 16; ++kt) {
    __syncthreads();  // tile kt resident; prev reads done
    if (kt < 15) stage(kt + 1, (kt + 1) & 1);
    const char* a0 = (const char*)sA[kt & 1];
    const char* b0 = (const char*)sB[kt & 1];
    bf16x8 af[4], bfr[4];
#pragma unroll
    for (int m = 0; m < 4; ++m) {
      const int row = m * 16 + lr;
      af[m] = *(const bf16x8*)(a0 + row * 64 + ((lg * 16) ^ ((row & 3) << 4)));
    }
#pragma unroll
    for (int n = 0; n < 4; ++n) {
      const int row = wn + n * 16 + lr;
      bfr[n] = *(const bf16x8*)(b0 + row * 64 + ((lg * 16) ^ ((row & 3) << 4)));
    }
#pragma unroll
    for (int m = 0; m < 4; ++m)
#pragma unroll
      for (int n = 0; n < 4; ++n)
        acc[m][n] = __builtin_amdgcn_mfma_f32_16x16x32_bf16(af[m], bfr[n], acc[m][n], 0, 0, 0);
  }

  // Epilogue: bf16 partials. C/D: col = lane&15, row = (lane>>4)*4 + reg.
  unsigned short* Pz = P + (long long)blockIdx.z * (4096LL * 256);
  const int r0 = rm + lg * 4;
#pragma unroll
  for (int n = 0; n < 4; ++n) {
    const int cc = wn + n * 16 + lr;
#pragma unroll
    for (int m = 0; m < 4; ++m)
#pragma unroll
      for (int i = 0; i < 4; ++i)
        Pz[(long long)(r0 + m * 16 + i) * 256 + cc] = f2bf(acc[m][n][i]);
  }
}

// Sum 8 bf16 split-K partial slices -> bf16 t (fp32 accumulate)
__global__ void reduce8(const ushort4* __restrict__ P, ushort4* __restrict__ t) {
  const int S = 4096 * 256 / 4;  // 262144 ushort4 per slice
  int i = blockIdx.x * 256 + threadIdx.x;
  float sx = 0, sy = 0, sz = 0, sw = 0;
#pragma unroll
  for (int z = 0; z < 8; ++z) {
    ushort4 v = P[i + z * S];
    sx += bf2f(v.x); sy += bf2f(v.y); sz += bf2f(v.z); sw += bf2f(v.w);
  }
  ushort4 o;
  o.x = f2bf(sx); o.y = f2bf(sy); o.z = f2bf(sz); o.w = f2bf(sw);
  t[i] = o;
}

// ---------------------------------------------------------------------------
// GEMM2 (unchanged, proven ~write-floor): out = t @ V^T + bias, fp32 out.
// BM=BN=128, nkt=8, XOR-swizzled both-sides.
// ---------------------------------------------------------------------------
__global__ __launch_bounds__(256)
void gemm2(const unsigned short* __restrict__ A,
           const unsigned short* __restrict__ B,
           const float* __restrict__ bias,
           float* __restrict__ C) {
  __shared__ __align__(16) unsigned short sA[2][128 * 32];
  __shared__ __align__(16) unsigned short sB[2][128 * 32];

  const int tid = threadIdx.x;
  const int l = tid & 63;
  const int w = tid >> 6;
  const int wm = (w >> 1) * 64;
  const int wn = (w & 1) * 64;
  const int rm = blockIdx.x * 128;
  const int rn = blockIdx.y * 128;
  const int lr = l & 15;
  const int lg = l >> 4;

  auto stage = [&](int kt, int buf) {
    const int k0 = kt * 32;
#pragma unroll
    for (int is = 0; is < 2; ++is) {
      int s = is * 256 + tid;
      int r = s >> 2;
      gload_lds16(B + (long long)(rn + r) * 256 + k0 + 8 * ((s & 3) ^ (r & 3)),
                  (char*)sB[buf] + s * 16);
    }
#pragma unroll
    for (int is = 0; is < 2; ++is) {
      int s = is * 256 + tid;
      int r = s >> 2;
      gload_lds16(A + (long long)(rm + r) * 256 + k0 + 8 * ((s & 3) ^ (r & 3)),
                  (char*)sA[buf] + s * 16);
    }
  };

  f32x4 acc[4][4] = {};

  stage(0, 0);
  for (int kt = 0; kt < 8; ++kt) {
    __syncthreads();
    if (kt < 7) stage(kt + 1, (kt + 1) & 1);
    const char* a0 = (const char*)sA[kt & 1];
    const char* b0 = (const char*)sB[kt & 1];
    bf16x8 af[4], bfr[4];
#pragma unroll
    for (int m = 0; m < 4; ++m) {
      const int row = wm + m * 16 + lr;
      af[m] = *(const bf16x8*)(a0 + row * 64 + ((lg * 16) ^ ((row & 3) << 4)));
    }
#pragma unroll
    for (int n = 0; n < 4; ++n) {
      const int row = wn + n * 16 + lr;
      bfr[n] = *(const bf16x8*)(b0 + row * 64 + ((lg * 16) ^ ((row & 3) << 4)));
    }
#pragma unroll
    for (int m = 0; m < 4; ++m)
#pragma unroll
      for (int n = 0; n < 4; ++n)
        acc[m][n] = __builtin_amdgcn_mfma_f32_16x16x32_bf16(af[m], bfr[n], acc[m][n], 0, 0, 0);
  }

  const int r0 = rm + wm + lg * 4;
  const int c0 = rn + wn + lr;
#pragma unroll
  for (int n = 0; n < 4; ++n) {
    const int cc = c0 + n * 16;
    const float badd = bias[cc];
#pragma unroll
    for (int m = 0; m < 4; ++m)
#pragma unroll
      for (int i = 0; i < 4; ++i)
        C[(long long)(r0 + m * 16 + i) * 4096 + cc] = acc[m][n][i] + badd;
  }
}

extern "C" void kernel_launch(void* const* d_in, const int* in_sizes, int n_in,
                              void* d_out, int out_size, void* d_ws, size_t ws_size,
                              hipStream_t stream) {
  const float* x    = (const float*)d_in[0];  // [4096,4096]
  const float* U    = (const float*)d_in[1];  // [256,4096]
  const float* V    = (const float*)d_in[2];  // [4096,256]
  const float* bias = (const float*)d_in[3];  // [4096]
  float* out = (float*)d_out;                 // [4096,4096] fp32

  // Workspace (54 MB):
  //  [0,16MB)   P: bf16 split-K partials [8][4096][256]
  //  [16,18MB)  t bf16 [4096][256]
  //  [18,20MB)  U bf16 [256][4096]
  //  [20,22MB)  V bf16 [4096][256]
  //  [22,54MB)  xb bf16 [4096][4096]
  char* ws = (char*)d_ws;
  unsigned short* P   = (unsigned short*)ws;
  unsigned short* tb  = (unsigned short*)(ws + (16u << 20));
  unsigned short* Ub  = (unsigned short*)(ws + (18u << 20));
  unsigned short* Vb  = (unsigned short*)(ws + (20u << 20));
  unsigned short* xb  = (unsigned short*)(ws + (22u << 20));

  prep<<<2048, 256, 0, stream>>>((const float4*)x, (const float4*)U, (const float4*)V,
                                 (ushort4*)xb, (ushort4*)Ub, (ushort4*)Vb);

  // GEMM1: grid 64 M-blocks x 8 z = 512 blocks (2/CU, capacity 4).
  dim3 g1(64, 1, 8);
  gemm1_bf16<<<g1, 256, 0, stream>>>(xb, Ub, P);

  reduce8<<<1024, 256, 0, stream>>>((const ushort4*)P, (ushort4*)tb);

  // GEMM2: grid 32x32.
  dim3 g2(32, 32, 1);
  gemm2<<<g2, 256, 0, stream>>>(tb, Vb, bias, out);
}